// Round 1
// baseline (3957.318 us; speedup 1.0000x reference)
//
#include <hip/hip_runtime.h>
#include <cstdint>
#include <math.h>

#define NB_B   16
#define NB_T   511
#define NB_S   512
#define NB_OBS 60
#define NB_D   1024
#define NB_H   16
#define NB_L   8
#define NB_DFF 4096
#define NB_HID 100
#define NB_OUT 30
#define NB_M   8192   // B*S rows

typedef __attribute__((ext_vector_type(8))) short  short8;
typedef __attribute__((ext_vector_type(4))) short  short4v;
typedef __attribute__((ext_vector_type(4))) float  f32x4;
typedef __attribute__((ext_vector_type(8))) __bf16 bf16x8;

__device__ __forceinline__ short f2bf(float f) {
  union { float f; unsigned u; } a; a.f = f;
  unsigned u = a.u + 0x7fffu + ((a.u >> 16) & 1u);   // RTNE
  return (short)(u >> 16);
}

__device__ __forceinline__ void load_lds16(const void* g, void* l) {
  __builtin_amdgcn_global_load_lds(
      (__attribute__((address_space(1))) unsigned int*)(uintptr_t)g,
      (__attribute__((address_space(3))) unsigned int*)(unsigned)(uintptr_t)l,
      16, 0, 0);
}

__device__ __forceinline__ f32x4 mfma16(short8 a, short8 b, f32x4 c) {
  return __builtin_amdgcn_mfma_f32_16x16x32_bf16(
      __builtin_bit_cast(bf16x8, a), __builtin_bit_cast(bf16x8, b), c, 0, 0, 0);
}

__device__ __forceinline__ float gelu_exact(float v) {
  return 0.5f * v * (1.f + erff(v * 0.70710678118654752f));
}

// ---------------------------------------------------------------------------
// Weight transpose + fp32->bf16 convert: src (R,C) fp32 -> dst (C,R) bf16 bits
// ---------------------------------------------------------------------------
__global__ __launch_bounds__(256) void tconv_kernel(
    const float* __restrict__ src, short* __restrict__ dst,
    int R, int C, size_t sstride, size_t dstride) {
  __shared__ float t[32][33];
  const float* s0 = src + blockIdx.z * sstride;
  short* d0 = dst + blockIdx.z * dstride;
  const int c0 = blockIdx.x * 32, r0 = blockIdx.y * 32;
  const int tx = threadIdx.x & 31, ty = threadIdx.x >> 5;
#pragma unroll
  for (int i = 0; i < 4; i++)
    t[ty + 8 * i][tx] = s0[(size_t)(r0 + ty + 8 * i) * C + c0 + tx];
  __syncthreads();
#pragma unroll
  for (int i = 0; i < 4; i++)
    d0[(size_t)(c0 + ty + 8 * i) * R + r0 + tx] = f2bf(t[tx][ty + 8 * i]);
}

// ---------------------------------------------------------------------------
// Token + positional embedding -> x fp32 (M, D)
// ---------------------------------------------------------------------------
__global__ __launch_bounds__(256) void embed_kernel(
    const float* __restrict__ states, const float* __restrict__ goals,
    const float* __restrict__ Wtok, const float* __restrict__ btok,
    const float* __restrict__ pos, float* __restrict__ x) {
  const int row = blockIdx.x;              // b*512 + s
  const int b = row >> 9, s = row & (NB_S - 1);
  __shared__ float tok[NB_OBS];
  if (threadIdx.x < NB_OBS)
    tok[threadIdx.x] = (s == 0)
        ? goals[b * NB_OBS + threadIdx.x]
        : states[((size_t)b * NB_T + (s - 1)) * NB_OBS + threadIdx.x];
  __syncthreads();
#pragma unroll
  for (int i = 0; i < 4; i++) {
    const int d = threadIdx.x + i * 256;
    float acc = btok[d] + pos[(size_t)s * NB_D + d];
    for (int o = 0; o < NB_OBS; o++) acc += tok[o] * Wtok[o * NB_D + d];
    x[(size_t)row * NB_D + d] = acc;
  }
}

// ---------------------------------------------------------------------------
// LayerNorm: fp32 (rows, D) -> OutT (short=bf16 bits, or float)
// ---------------------------------------------------------------------------
template <typename OutT>
__global__ __launch_bounds__(256) void ln_kernel(
    const float* __restrict__ xin, const float* __restrict__ gam,
    const float* __restrict__ bet, OutT* __restrict__ outp) {
  const int row = blockIdx.x;
  const int tid = threadIdx.x;
  const float4 v = ((const float4*)(xin + (size_t)row * NB_D))[tid];
  float s = v.x + v.y + v.z + v.w;
  float s2 = v.x * v.x + v.y * v.y + v.z * v.z + v.w * v.w;
#pragma unroll
  for (int o = 32; o; o >>= 1) {
    s += __shfl_down(s, o, 64);
    s2 += __shfl_down(s2, o, 64);
  }
  __shared__ float red[8];
  if ((tid & 63) == 0) { red[tid >> 6] = s; red[4 + (tid >> 6)] = s2; }
  __syncthreads();
  const float S1 = red[0] + red[1] + red[2] + red[3];
  const float S2 = red[4] + red[5] + red[6] + red[7];
  const float mean = S1 * (1.f / NB_D);
  const float var = S2 * (1.f / NB_D) - mean * mean;
  const float rs = rsqrtf(var + 1e-5f);
  const float4 g4 = ((const float4*)gam)[tid];
  const float4 b4 = ((const float4*)bet)[tid];
  const float o0 = (v.x - mean) * rs * g4.x + b4.x;
  const float o1 = (v.y - mean) * rs * g4.y + b4.y;
  const float o2 = (v.z - mean) * rs * g4.z + b4.z;
  const float o3 = (v.w - mean) * rs * g4.w + b4.w;
  if constexpr (sizeof(OutT) == 2) {
    short4v r = {f2bf(o0), f2bf(o1), f2bf(o2), f2bf(o3)};
    *(short4v*)((short*)outp + (size_t)row * NB_D + tid * 4) = r;
  } else {
    ((float4*)((float*)outp + (size_t)row * NB_D))[tid] = make_float4(o0, o1, o2, o3);
  }
}

// ---------------------------------------------------------------------------
// bf16 MFMA GEMM, m97 structure: C(M,N) = A(M,K)bf16 * Bt(N,K)bf16^T + bias
// 128x128 tile, BK=32, 4 waves, global_load_lds staging w/ XOR slot swizzle.
// ---------------------------------------------------------------------------
template <int ACT, bool RESID, typename OutT>
__device__ __forceinline__ void gemm_core(
    const short* __restrict__ A, const short* __restrict__ Bt,
    const float* __restrict__ bias, const float* __restrict__ resid,
    OutT* __restrict__ C, int N, int K) {
  __shared__ short As[128][32];  // rows = M, 4 x 16B slots per row, swizzled
  __shared__ short Bs[128][32];  // rows = N
  const int bm = blockIdx.y * 128, bn = blockIdx.x * 128;
  const int tid = threadIdx.x;
  const int w = tid >> 6, lane = tid & 63;
  const int wr = (w >> 1) * 64, wc = (w & 1) * 64;
  const int rr = lane & 15, sg = lane >> 4;

  f32x4 acc[4][4];
#pragma unroll
  for (int i = 0; i < 4; i++)
#pragma unroll
    for (int j = 0; j < 4; j++) acc[i][j] = f32x4{0.f, 0.f, 0.f, 0.f};

  const int srow0 = w * 32 + (lane >> 2);  // staging row (this wave: +0 / +16)
  const int sslot = lane & 3;              // physical 16B slot

  for (int k0 = 0; k0 < K; k0 += 32) {
    __syncthreads();
#pragma unroll
    for (int inst = 0; inst < 2; inst++) {
      const int r = srow0 + inst * 16;
      const int sl = sslot ^ ((r >> 1) & 3);  // pre-swizzled global source
      load_lds16(A + (size_t)(bm + r) * K + k0 + sl * 8, &As[w * 32 + inst * 16][0]);
      load_lds16(Bt + (size_t)(bn + r) * K + k0 + sl * 8, &Bs[w * 32 + inst * 16][0]);
    }
    __syncthreads();
    short8 a[4], b[4];
#pragma unroll
    for (int i = 0; i < 4; i++) {
      const int r = wr + i * 16 + rr;
      a[i] = *(const short8*)&As[r][(sg ^ ((r >> 1) & 3)) * 8];
      const int c = wc + i * 16 + rr;
      b[i] = *(const short8*)&Bs[c][(sg ^ ((c >> 1) & 3)) * 8];
    }
#pragma unroll
    for (int i = 0; i < 4; i++)
#pragma unroll
      for (int j = 0; j < 4; j++) acc[i][j] = mfma16(a[i], b[j], acc[i][j]);
  }

#pragma unroll
  for (int j = 0; j < 4; j++) {
    const int col = bn + wc + j * 16 + rr;
    const float bv = bias[col];
#pragma unroll
    for (int i = 0; i < 4; i++) {
#pragma unroll
      for (int q = 0; q < 4; q++) {
        const int row = bm + wr + i * 16 + sg * 4 + q;
        float v = acc[i][j][q] + bv;
        if constexpr (RESID) v += resid[(size_t)row * N + col];
        if constexpr (ACT == 1) v = gelu_exact(v);
        if constexpr (sizeof(OutT) == 2) C[(size_t)row * N + col] = (OutT)f2bf(v);
        else C[(size_t)row * N + col] = v;
      }
    }
  }
}

template <int ACT, bool RESID, typename OutT>
__global__ __launch_bounds__(256) void gemm_bt(
    const short* __restrict__ A, const short* __restrict__ Bt,
    const float* __restrict__ bias, const float* __restrict__ resid,
    OutT* __restrict__ C, int N, int K) {
  gemm_core<ACT, RESID, OutT>(A, Bt, bias, resid, C, N, K);
}

__global__ __launch_bounds__(256) void gemm_qkv_kernel(
    const short* __restrict__ A, const short* __restrict__ Wt3,
    const float* __restrict__ bq, const float* __restrict__ bk,
    const float* __restrict__ bv, short* __restrict__ outqkv) {
  const int z = blockIdx.z;
  const short* Bt = Wt3 + (size_t)z * NB_D * NB_D;
  const float* bias = (z == 0) ? bq : ((z == 1) ? bk : bv);
  short* C = outqkv + (size_t)z * NB_M * NB_D;
  gemm_core<0, false, short>(A, Bt, bias, nullptr, C, NB_D, NB_D);
}

// ---------------------------------------------------------------------------
// Fused causal flash attention, bf16 MFMA. Block = (qt, h, b); 4 waves,
// each wave owns 16 q rows; K/V tiles of 64.
// ---------------------------------------------------------------------------
__global__ __launch_bounds__(256) void attn_kernel(
    const short* __restrict__ qkv, short* __restrict__ out) {
  const int qt = blockIdx.x, hh = blockIdx.y, bb = blockIdx.z;
  const int tid = threadIdx.x;
  const int w = tid >> 6, lane = tid & 63;
  const int rr = lane & 15, sg = lane >> 4;

  const size_t MD = (size_t)NB_M * NB_D;
  const short* Q = qkv;
  const short* K = qkv + MD;
  const short* V = qkv + 2 * MD;

  __shared__ short Ks[64][64];     // rows = s_k, cols = dh (8x16B slots, swizzled)
  __shared__ short Vt[64][64];     // rows = dh, cols = s_k (swizzled)
  __shared__ short Ps[4][16][64];  // per-wave P, rows = s_q (swizzled)

  short8 qf[2];
  {
    const size_t qrow = (size_t)bb * NB_S + qt * 64 + w * 16 + rr;
#pragma unroll
    for (int ks = 0; ks < 2; ks++)
      qf[ks] = *(const short8*)&Q[qrow * NB_D + hh * 64 + ks * 32 + sg * 8];
  }

  float mrow[4], lrow[4];
  f32x4 o[4];
#pragma unroll
  for (int j = 0; j < 4; j++) { mrow[j] = -INFINITY; lrow[j] = 0.f; }
#pragma unroll
  for (int nb = 0; nb < 4; nb++) o[nb] = f32x4{0.f, 0.f, 0.f, 0.f};

  for (int kt = 0; kt <= qt; kt++) {
    __syncthreads();
    {  // stage K tile via global_load_lds, pre-swizzled source
      const int p = lane & 7;
#pragma unroll
      for (int inst = 0; inst < 2; inst++) {
        const int r = w * 16 + inst * 8 + (lane >> 3);
        const int sl = p ^ (r & 7);
        load_lds16(K + ((size_t)bb * NB_S + kt * 64 + r) * NB_D + hh * 64 + sl * 8,
                   &Ks[w * 16 + inst * 8][0]);
      }
    }
    {  // stage V transposed (register path)
#pragma unroll
      for (int cc = 0; cc < 2; cc++) {
        const int c = tid * 2 + cc;
        const int sk = c >> 3, sl = c & 7;
        short8 vv = *(const short8*)&V[((size_t)bb * NB_S + kt * 64 + sk) * NB_D + hh * 64 + sl * 8];
        const int ss = sk >> 3;
#pragma unroll
        for (int j = 0; j < 8; j++) {
          const int dh = sl * 8 + j;
          Vt[dh][(ss ^ (dh & 7)) * 8 + (sk & 7)] = vv[j];
        }
      }
    }
    __syncthreads();

    // scores S = Q * K^T
    f32x4 sf[4];
#pragma unroll
    for (int nb = 0; nb < 4; nb++) sf[nb] = f32x4{0.f, 0.f, 0.f, 0.f};
#pragma unroll
    for (int ks = 0; ks < 2; ks++) {
#pragma unroll
      for (int nb = 0; nb < 4; nb++) {
        const int ck = nb * 16 + rr;
        short8 kf = *(const short8*)&Ks[ck][((ks * 4 + sg) ^ (ck & 7)) * 8];
        sf[nb] = mfma16(qf[ks], kf, sf[nb]);
      }
    }
    // scale + causal mask + row max
    const int rbase = qt * 64 + w * 16 + sg * 4;
    float pmax[4] = {-INFINITY, -INFINITY, -INFINITY, -INFINITY};
#pragma unroll
    for (int nb = 0; nb < 4; nb++) {
      const int cg = kt * 64 + nb * 16 + rr;
#pragma unroll
      for (int j = 0; j < 4; j++) {
        float sv = sf[nb][j] * 0.125f;
        if (cg > rbase + j) sv = -INFINITY;
        sf[nb][j] = sv;
        pmax[j] = fmaxf(pmax[j], sv);
      }
    }
#pragma unroll
    for (int o1 = 1; o1 < 16; o1 <<= 1)
#pragma unroll
      for (int j = 0; j < 4; j++)
        pmax[j] = fmaxf(pmax[j], __shfl_xor(pmax[j], o1, 64));

    float resc[4], psum[4];
#pragma unroll
    for (int j = 0; j < 4; j++) {
      const float mn = fmaxf(mrow[j], pmax[j]);
      resc[j] = __expf(mrow[j] - mn);
      mrow[j] = mn;
      psum[j] = 0.f;
    }
#pragma unroll
    for (int nb = 0; nb < 4; nb++)
#pragma unroll
      for (int j = 0; j < 4; j++) {
        const float p = __expf(sf[nb][j] - mrow[j]);
        sf[nb][j] = p;
        psum[j] += p;
      }
#pragma unroll
    for (int o1 = 1; o1 < 16; o1 <<= 1)
#pragma unroll
      for (int j = 0; j < 4; j++) psum[j] += __shfl_xor(psum[j], o1, 64);
#pragma unroll
    for (int j = 0; j < 4; j++) lrow[j] = lrow[j] * resc[j] + psum[j];
#pragma unroll
    for (int nb = 0; nb < 4; nb++)
#pragma unroll
      for (int j = 0; j < 4; j++) o[nb][j] *= resc[j];

    // P -> wave-private LDS (C-layout -> A-layout), then PV
#pragma unroll
    for (int nb = 0; nb < 4; nb++) {
      const int ck = nb * 16 + rr;
      const int ss = ck >> 3;
#pragma unroll
      for (int j = 0; j < 4; j++) {
        const int rq = sg * 4 + j;
        Ps[w][rq][(ss ^ (rq & 7)) * 8 + (ck & 7)] = f2bf(sf[nb][j]);
      }
    }
#pragma unroll
    for (int ks = 0; ks < 2; ks++) {
      short8 pf = *(const short8*)&Ps[w][rr][((ks * 4 + sg) ^ (rr & 7)) * 8];
#pragma unroll
      for (int nb = 0; nb < 4; nb++) {
        const int dh = nb * 16 + rr;
        short8 vf = *(const short8*)&Vt[dh][((ks * 4 + sg) ^ (dh & 7)) * 8];
        o[nb] = mfma16(pf, vf, o[nb]);
      }
    }
  }

  {
    const size_t orow0 = (size_t)bb * NB_S + qt * 64 + w * 16;
#pragma unroll
    for (int nb = 0; nb < 4; nb++)
#pragma unroll
      for (int j = 0; j < 4; j++) {
        const float v = o[nb][j] / lrow[j];
        out[(orow0 + sg * 4 + j) * NB_D + hh * 64 + nb * 16 + rr] = f2bf(v);
      }
  }
}

// ---------------------------------------------------------------------------
// Head: silu(xf @ Wh1 + bh1) @ Wh2 + bh2, fp32. Block = 16 token rows.
// ---------------------------------------------------------------------------
__global__ __launch_bounds__(256) void head_kernel(
    const float* __restrict__ xf, const float* __restrict__ Wh1,
    const float* __restrict__ bh1, const float* __restrict__ Wh2,
    const float* __restrict__ bh2, float* __restrict__ outp) {
  __shared__ float xs[16][NB_D];
  __shared__ float hs[16][NB_HID];
  const int g0 = blockIdx.x * 16;
  for (int r = 0; r < 16; r++) {
    const int g = g0 + r;
    const int b = g / NB_T, t = g % NB_T;
    ((float4*)xs[r])[threadIdx.x] =
        ((const float4*)(xf + ((size_t)(b * NB_S + 1 + t)) * NB_D))[threadIdx.x];
  }
  __syncthreads();
  for (int idx = threadIdx.x; idx < 16 * NB_HID; idx += 256) {
    const int r = idx / NB_HID, j = idx % NB_HID;
    float acc = bh1[j];
    for (int k = 0; k < NB_D; k++) acc += xs[r][k] * Wh1[k * NB_HID + j];
    hs[r][j] = acc / (1.f + __expf(-acc));
  }
  __syncthreads();
  for (int idx = threadIdx.x; idx < 16 * NB_OUT; idx += 256) {
    const int r = idx / NB_OUT, j = idx % NB_OUT;
    float acc = bh2[j];
#pragma unroll
    for (int k = 0; k < NB_HID; k++) acc += hs[r][k] * Wh2[k * NB_OUT + j];
    outp[(size_t)(g0 + r) * NB_OUT + j] = acc;
  }
}

// ---------------------------------------------------------------------------
extern "C" void kernel_launch(void* const* d_in, const int* in_sizes, int n_in,
                              void* d_out, int out_size, void* d_ws, size_t ws_size,
                              hipStream_t stream) {
  const float* states = (const float*)d_in[0];
  const float* goals  = (const float*)d_in[1];
  const float* Wtok   = (const float*)d_in[2];
  const float* btok   = (const float*)d_in[3];
  const float* pos    = (const float*)d_in[4];
  const float* ln1_g  = (const float*)d_in[5];
  const float* ln1_b  = (const float*)d_in[6];
  const float* Wq     = (const float*)d_in[7];
  const float* bq     = (const float*)d_in[8];
  const float* Wk     = (const float*)d_in[9];
  const float* bk     = (const float*)d_in[10];
  const float* Wv     = (const float*)d_in[11];
  const float* bv     = (const float*)d_in[12];
  const float* Wp     = (const float*)d_in[13];
  const float* bp     = (const float*)d_in[14];
  const float* ln2_g  = (const float*)d_in[15];
  const float* ln2_b  = (const float*)d_in[16];
  const float* Wm1    = (const float*)d_in[17];
  const float* bm1    = (const float*)d_in[18];
  const float* Wm2    = (const float*)d_in[19];
  const float* bm2    = (const float*)d_in[20];
  const float* lnf_g  = (const float*)d_in[21];
  const float* lnf_b  = (const float*)d_in[22];
  const float* Wh1    = (const float*)d_in[23];
  const float* bh1    = (const float*)d_in[24];
  const float* Wh2    = (const float*)d_in[25];
  const float* bh2    = (const float*)d_in[26];

  char* wsp = (char*)d_ws;
  size_t off = 0;
  auto carve = [&](size_t bytes) -> char* {
    char* p = wsp + off;
    off += (bytes + 1023) & ~(size_t)1023;
    return p;
  };
  short* Wqkv_t = (short*)carve((size_t)NB_L * 3 * NB_D * NB_D * 2);   // (l,3,N=D,K=D)
  short* Wp_t   = (short*)carve((size_t)NB_L * NB_D * NB_D * 2);       // (l,N=D,K=D)
  short* Wm1_t  = (short*)carve((size_t)NB_L * NB_DFF * NB_D * 2);     // (l,N=DFF,K=D)
  short* Wm2_t  = (short*)carve((size_t)NB_L * NB_D * NB_DFF * 2);     // (l,N=D,K=DFF)
  float* x      = (float*)carve((size_t)NB_M * NB_D * 4);
  short* h      = (short*)carve((size_t)NB_M * NB_D * 2);
  short* qkvb   = (short*)carve((size_t)3 * NB_M * NB_D * 2);
  short* mlp    = (short*)carve((size_t)NB_M * NB_DFF * 2);
  short* attout = mlp;           // alias: dead before mlp is written
  float* xf     = (float*)qkvb;  // alias: qkv dead after last attention

  const dim3 thr(256);
  const size_t DD = (size_t)NB_D * NB_D;
  const size_t DF = (size_t)NB_D * NB_DFF;

  // weight transpose+convert (fp32 (K,N) -> bf16 (N,K))
  tconv_kernel<<<dim3(32, 32, NB_L), thr, 0, stream>>>(Wq, Wqkv_t + 0 * DD, NB_D, NB_D, DD, 3 * DD);
  tconv_kernel<<<dim3(32, 32, NB_L), thr, 0, stream>>>(Wk, Wqkv_t + 1 * DD, NB_D, NB_D, DD, 3 * DD);
  tconv_kernel<<<dim3(32, 32, NB_L), thr, 0, stream>>>(Wv, Wqkv_t + 2 * DD, NB_D, NB_D, DD, 3 * DD);
  tconv_kernel<<<dim3(32, 32, NB_L), thr, 0, stream>>>(Wp, Wp_t, NB_D, NB_D, DD, DD);
  tconv_kernel<<<dim3(128, 32, NB_L), thr, 0, stream>>>(Wm1, Wm1_t, NB_D, NB_DFF, DF, DF);
  tconv_kernel<<<dim3(32, 128, NB_L), thr, 0, stream>>>(Wm2, Wm2_t, NB_DFF, NB_D, DF, DF);

  embed_kernel<<<NB_M, thr, 0, stream>>>(states, goals, Wtok, btok, pos, x);

  for (int l = 0; l < NB_L; l++) {
    ln_kernel<short><<<NB_M, thr, 0, stream>>>(x, ln1_g + l * NB_D, ln1_b + l * NB_D, h);
    gemm_qkv_kernel<<<dim3(NB_D / 128, NB_M / 128, 3), thr, 0, stream>>>(
        h, Wqkv_t + (size_t)l * 3 * DD, bq + l * NB_D, bk + l * NB_D, bv + l * NB_D, qkvb);
    attn_kernel<<<dim3(NB_S / 64, NB_H, NB_B), thr, 0, stream>>>(qkvb, attout);
    gemm_bt<0, true, float><<<dim3(NB_D / 128, NB_M / 128), thr, 0, stream>>>(
        attout, Wp_t + (size_t)l * DD, bp + l * NB_D, x, x, NB_D, NB_D);
    ln_kernel<short><<<NB_M, thr, 0, stream>>>(x, ln2_g + l * NB_D, ln2_b + l * NB_D, h);
    gemm_bt<1, false, short><<<dim3(NB_DFF / 128, NB_M / 128), thr, 0, stream>>>(
        h, Wm1_t + (size_t)l * DF, bm1 + l * NB_DFF, nullptr, mlp, NB_DFF, NB_D);
    gemm_bt<0, true, float><<<dim3(NB_D / 128, NB_M / 128), thr, 0, stream>>>(
        mlp, Wm2_t + (size_t)l * DF, bm2 + l * NB_D, x, x, NB_D, NB_DFF);
  }

  ln_kernel<float><<<NB_M, thr, 0, stream>>>(x, lnf_g, lnf_b, xf);
  head_kernel<<<NB_T, thr, 0, stream>>>(xf, Wh1, bh1, Wh2, bh2, (float*)d_out);
}

// Round 2
// 3385.203 us; speedup vs baseline: 1.1690x; 1.1690x over previous
//
#include <hip/hip_runtime.h>
#include <cstdint>
#include <math.h>

#define NB_B   16
#define NB_T   511
#define NB_S   512
#define NB_OBS 60
#define NB_D   1024
#define NB_H   16
#define NB_L   8
#define NB_DFF 4096
#define NB_HID 100
#define NB_OUT 30
#define NB_M   8192   // B*S rows

typedef __attribute__((ext_vector_type(8))) short  short8;
typedef __attribute__((ext_vector_type(4))) short  short4v;
typedef __attribute__((ext_vector_type(4))) float  f32x4;
typedef __attribute__((ext_vector_type(8))) __bf16 bf16x8;

__device__ __forceinline__ short f2bf(float f) {
  union { float f; unsigned u; } a; a.f = f;
  unsigned u = a.u + 0x7fffu + ((a.u >> 16) & 1u);   // RTNE
  return (short)(u >> 16);
}

__device__ __forceinline__ void load_lds16(const void* g, void* l) {
  __builtin_amdgcn_global_load_lds(
      (__attribute__((address_space(1))) unsigned int*)(uintptr_t)g,
      (__attribute__((address_space(3))) unsigned int*)(unsigned)(uintptr_t)l,
      16, 0, 0);
}

__device__ __forceinline__ f32x4 mfma16(short8 a, short8 b, f32x4 c) {
  return __builtin_amdgcn_mfma_f32_16x16x32_bf16(
      __builtin_bit_cast(bf16x8, a), __builtin_bit_cast(bf16x8, b), c, 0, 0, 0);
}

__device__ __forceinline__ float gelu_exact(float v) {
  return 0.5f * v * (1.f + erff(v * 0.70710678118654752f));
}

// ---------------------------------------------------------------------------
// Weight transpose + fp32->bf16 convert: src (R,C) fp32 -> dst (C,R) bf16 bits
// ---------------------------------------------------------------------------
__global__ __launch_bounds__(256) void tconv_kernel(
    const float* __restrict__ src, short* __restrict__ dst,
    int R, int C, size_t sstride, size_t dstride) {
  __shared__ float t[32][33];
  const float* s0 = src + blockIdx.z * sstride;
  short* d0 = dst + blockIdx.z * dstride;
  const int c0 = blockIdx.x * 32, r0 = blockIdx.y * 32;
  const int tx = threadIdx.x & 31, ty = threadIdx.x >> 5;
#pragma unroll
  for (int i = 0; i < 4; i++)
    t[ty + 8 * i][tx] = s0[(size_t)(r0 + ty + 8 * i) * C + c0 + tx];
  __syncthreads();
#pragma unroll
  for (int i = 0; i < 4; i++)
    d0[(size_t)(c0 + ty + 8 * i) * R + r0 + tx] = f2bf(t[tx][ty + 8 * i]);
}

// ---------------------------------------------------------------------------
// Head weight prep: Wh1 (1024,100) fp32 -> Wh1t (128,1024) bf16 (zero-padded),
// bh1 (100) -> bh1p (128) fp32 zero-padded.
// ---------------------------------------------------------------------------
__global__ __launch_bounds__(256) void whead_prep(
    const float* __restrict__ Wh1, const float* __restrict__ bh1,
    short* __restrict__ Wh1t, float* __restrict__ bh1p) {
  const int idx = blockIdx.x * 256 + threadIdx.x;   // 0 .. 128*1024-1
  const int n = idx >> 10, k = idx & 1023;
  Wh1t[idx] = (n < NB_HID) ? f2bf(Wh1[k * NB_HID + n]) : (short)0;
  if (idx < 128) bh1p[idx] = (idx < NB_HID) ? bh1[idx] : 0.f;
}

// ---------------------------------------------------------------------------
// Token + positional embedding -> x fp32 (M, D)
// ---------------------------------------------------------------------------
__global__ __launch_bounds__(256) void embed_kernel(
    const float* __restrict__ states, const float* __restrict__ goals,
    const float* __restrict__ Wtok, const float* __restrict__ btok,
    const float* __restrict__ pos, float* __restrict__ x) {
  const int row = blockIdx.x;              // b*512 + s
  const int b = row >> 9, s = row & (NB_S - 1);
  __shared__ float tok[NB_OBS];
  if (threadIdx.x < NB_OBS)
    tok[threadIdx.x] = (s == 0)
        ? goals[b * NB_OBS + threadIdx.x]
        : states[((size_t)b * NB_T + (s - 1)) * NB_OBS + threadIdx.x];
  __syncthreads();
#pragma unroll
  for (int i = 0; i < 4; i++) {
    const int d = threadIdx.x + i * 256;
    float acc = btok[d] + pos[(size_t)s * NB_D + d];
    for (int o = 0; o < NB_OBS; o++) acc += tok[o] * Wtok[o * NB_D + d];
    x[(size_t)row * NB_D + d] = acc;
  }
}

// ---------------------------------------------------------------------------
// LayerNorm: fp32 (rows, D) -> OutT (short=bf16 bits, or float)
// ---------------------------------------------------------------------------
template <typename OutT>
__global__ __launch_bounds__(256) void ln_kernel(
    const float* __restrict__ xin, const float* __restrict__ gam,
    const float* __restrict__ bet, OutT* __restrict__ outp) {
  const int row = blockIdx.x;
  const int tid = threadIdx.x;
  const float4 v = ((const float4*)(xin + (size_t)row * NB_D))[tid];
  float s = v.x + v.y + v.z + v.w;
  float s2 = v.x * v.x + v.y * v.y + v.z * v.z + v.w * v.w;
#pragma unroll
  for (int o = 32; o; o >>= 1) {
    s += __shfl_down(s, o, 64);
    s2 += __shfl_down(s2, o, 64);
  }
  __shared__ float red[8];
  if ((tid & 63) == 0) { red[tid >> 6] = s; red[4 + (tid >> 6)] = s2; }
  __syncthreads();
  const float S1 = red[0] + red[1] + red[2] + red[3];
  const float S2 = red[4] + red[5] + red[6] + red[7];
  const float mean = S1 * (1.f / NB_D);
  const float var = S2 * (1.f / NB_D) - mean * mean;
  const float rs = rsqrtf(var + 1e-5f);
  const float4 g4 = ((const float4*)gam)[tid];
  const float4 b4 = ((const float4*)bet)[tid];
  const float o0 = (v.x - mean) * rs * g4.x + b4.x;
  const float o1 = (v.y - mean) * rs * g4.y + b4.y;
  const float o2 = (v.z - mean) * rs * g4.z + b4.z;
  const float o3 = (v.w - mean) * rs * g4.w + b4.w;
  if constexpr (sizeof(OutT) == 2) {
    short4v r = {f2bf(o0), f2bf(o1), f2bf(o2), f2bf(o3)};
    *(short4v*)((short*)outp + (size_t)row * NB_D + tid * 4) = r;
  } else {
    ((float4*)((float*)outp + (size_t)row * NB_D))[tid] = make_float4(o0, o1, o2, o3);
  }
}

// ---------------------------------------------------------------------------
// OLD m97-style 128x128 GEMM core (kept for the head GEMM, N=128).
// ---------------------------------------------------------------------------
template <int ACT, bool RESID, typename OutT>
__device__ __forceinline__ void gemm_core(
    const short* __restrict__ A, const short* __restrict__ Bt,
    const float* __restrict__ bias, const float* __restrict__ resid,
    OutT* __restrict__ C, int N, int K) {
  __shared__ short As[128][32];
  __shared__ short Bs[128][32];
  const int bm = blockIdx.y * 128, bn = blockIdx.x * 128;
  const int tid = threadIdx.x;
  const int w = tid >> 6, lane = tid & 63;
  const int wr = (w >> 1) * 64, wc = (w & 1) * 64;
  const int rr = lane & 15, sg = lane >> 4;

  f32x4 acc[4][4];
#pragma unroll
  for (int i = 0; i < 4; i++)
#pragma unroll
    for (int j = 0; j < 4; j++) acc[i][j] = f32x4{0.f, 0.f, 0.f, 0.f};

  const int srow0 = w * 32 + (lane >> 2);
  const int sslot = lane & 3;

  for (int k0 = 0; k0 < K; k0 += 32) {
    __syncthreads();
#pragma unroll
    for (int inst = 0; inst < 2; inst++) {
      const int r = srow0 + inst * 16;
      const int sl = sslot ^ ((r >> 1) & 3);
      load_lds16(A + (size_t)(bm + r) * K + k0 + sl * 8, &As[w * 32 + inst * 16][0]);
      load_lds16(Bt + (size_t)(bn + r) * K + k0 + sl * 8, &Bs[w * 32 + inst * 16][0]);
    }
    __syncthreads();
    short8 a[4], b[4];
#pragma unroll
    for (int i = 0; i < 4; i++) {
      const int r = wr + i * 16 + rr;
      a[i] = *(const short8*)&As[r][(sg ^ ((r >> 1) & 3)) * 8];
      const int c = wc + i * 16 + rr;
      b[i] = *(const short8*)&Bs[c][(sg ^ ((c >> 1) & 3)) * 8];
    }
#pragma unroll
    for (int i = 0; i < 4; i++)
#pragma unroll
      for (int j = 0; j < 4; j++) acc[i][j] = mfma16(a[i], b[j], acc[i][j]);
  }

#pragma unroll
  for (int j = 0; j < 4; j++) {
    const int col = bn + wc + j * 16 + rr;
    const float bv = bias[col];
#pragma unroll
    for (int i = 0; i < 4; i++) {
#pragma unroll
      for (int q = 0; q < 4; q++) {
        const int row = bm + wr + i * 16 + sg * 4 + q;
        float v = acc[i][j][q] + bv;
        if constexpr (RESID) v += resid[(size_t)row * N + col];
        if constexpr (ACT == 1) v = gelu_exact(v);
        if constexpr (ACT == 2) v = v / (1.f + __expf(-v));
        if constexpr (sizeof(OutT) == 2) C[(size_t)row * N + col] = (OutT)f2bf(v);
        else C[(size_t)row * N + col] = v;
      }
    }
  }
}

template <int ACT, bool RESID, typename OutT>
__global__ __launch_bounds__(256) void gemm_bt(
    const short* __restrict__ A, const short* __restrict__ Bt,
    const float* __restrict__ bias, const float* __restrict__ resid,
    OutT* __restrict__ C, int N, int K) {
  gemm_core<ACT, RESID, OutT>(A, Bt, bias, resid, C, N, K);
}

// ---------------------------------------------------------------------------
// NEW phase-pipelined GEMM (T2+T3+T4+T5): BM=128, BN=256, BK=64, 512 threads
// (8 waves = 2M x 4N, 64x64 per wave), 3 rotating K-tile LDS buffers (144 KiB),
// counted vmcnt(6) (prefetch depth 2 K-tiles, 6 gload_lds per thread per tile),
// 4 phases/K-tile: {ds_read frags | 2 stages -> barrier -> prio1 8xMFMA prio0
// -> barrier}. T2 slot swizzle: pre-swizzled global source + swizzled ds_read.
// ---------------------------------------------------------------------------
template <int ACT, bool RESID, typename OutT>
__device__ __forceinline__ void gemm8_core(
    const short* __restrict__ A, const short* __restrict__ Bt,
    const float* __restrict__ bias, const float* __restrict__ resid,
    OutT* __restrict__ C, int N, int K) {
  __shared__ short As[3][128][64];   // 48 KiB
  __shared__ short Bs[3][256][64];   // 96 KiB
  const int bm = blockIdx.y * 128, bn = blockIdx.x * 256;
  const int tid = threadIdx.x;
  const int w = tid >> 6, lane = tid & 63;
  const int wr = (w >> 2) * 64, wc = (w & 3) * 64;
  const int rr = lane & 15, sg = lane >> 4;
  const int lrow = lane >> 3;                       // 0..7 (row within 8-row wave chunk)
  const int lslot = (lane & 7) ^ lrow;              // pre-swizzled source slot

  // per-lane global base addresses for staging (rows advance by c*64)
  const short* Asrc = A + (size_t)(bm + w * 8 + lrow) * K + lslot * 8;
  const short* Bsrc = Bt + (size_t)(bn + w * 8 + lrow) * K + lslot * 8;

  auto stageA = [&](int buf, int c, int k0) {
    load_lds16(Asrc + (size_t)(c * 64) * K + k0, &As[buf][c * 64 + w * 8][0]);
  };
  auto stageB = [&](int buf, int c, int k0) {
    load_lds16(Bsrc + (size_t)(c * 64) * K + k0, &Bs[buf][c * 64 + w * 8][0]);
  };
  // issue order within a tile is fixed: B0,B1,B2,B3,A0,A1 (6 loads/thread)
  auto stage_tile = [&](int buf, int k0) {
    stageB(buf, 0, k0); stageB(buf, 1, k0); stageB(buf, 2, k0); stageB(buf, 3, k0);
    stageA(buf, 0, k0); stageA(buf, 1, k0);
  };

  f32x4 acc[4][4];
#pragma unroll
  for (int i = 0; i < 4; i++)
#pragma unroll
    for (int j = 0; j < 4; j++) acc[i][j] = f32x4{0.f, 0.f, 0.f, 0.f};

  const int nk = K >> 6;
  stage_tile(0, 0);
  stage_tile(1, 64);
  asm volatile("s_waitcnt vmcnt(6)" ::: "memory");
  asm volatile("s_barrier" ::: "memory");

  int bcur = 0, bnext = 1, bstage = 2;
  for (int t = 0; t < nk; ++t) {
    const bool do_stage = (t + 2 < nk);
    const int k2 = (t + 2) << 6;

    auto rdA = [&](int i, int kk) {
      const int r = wr + i * 16 + rr;
      return *(const short8*)&As[bcur][r][((kk * 4 + sg) ^ (r & 7)) * 8];
    };
    auto rdB = [&](int j, int kk) {
      const int r = wc + j * 16 + rr;
      return *(const short8*)&Bs[bcur][r][((kk * 4 + sg) ^ (r & 7)) * 8];
    };

    // ---- phase 0: i{0,1} x j{0,1}
    short8 a00 = rdA(0, 0), a01 = rdA(0, 1), a10 = rdA(1, 0), a11 = rdA(1, 1);
    short8 b00 = rdB(0, 0), b01 = rdB(0, 1), b10 = rdB(1, 0), b11 = rdB(1, 1);
    if (do_stage) { stageB(bstage, 0, k2); stageB(bstage, 1, k2); }
    asm volatile("s_barrier" ::: "memory");
    __builtin_amdgcn_s_setprio(1);
    acc[0][0] = mfma16(a00, b00, acc[0][0]); acc[0][0] = mfma16(a01, b01, acc[0][0]);
    acc[0][1] = mfma16(a00, b10, acc[0][1]); acc[0][1] = mfma16(a01, b11, acc[0][1]);
    acc[1][0] = mfma16(a10, b00, acc[1][0]); acc[1][0] = mfma16(a11, b01, acc[1][0]);
    acc[1][1] = mfma16(a10, b10, acc[1][1]); acc[1][1] = mfma16(a11, b11, acc[1][1]);
    __builtin_amdgcn_s_setprio(0);
    asm volatile("s_barrier" ::: "memory");

    // ---- phase 1: i{0,1} x j{2,3}
    short8 b20 = rdB(2, 0), b21 = rdB(2, 1), b30 = rdB(3, 0), b31 = rdB(3, 1);
    if (do_stage) { stageB(bstage, 2, k2); stageB(bstage, 3, k2); }
    asm volatile("s_barrier" ::: "memory");
    __builtin_amdgcn_s_setprio(1);
    acc[0][2] = mfma16(a00, b20, acc[0][2]); acc[0][2] = mfma16(a01, b21, acc[0][2]);
    acc[0][3] = mfma16(a00, b30, acc[0][3]); acc[0][3] = mfma16(a01, b31, acc[0][3]);
    acc[1][2] = mfma16(a10, b20, acc[1][2]); acc[1][2] = mfma16(a11, b21, acc[1][2]);
    acc[1][3] = mfma16(a10, b30, acc[1][3]); acc[1][3] = mfma16(a11, b31, acc[1][3]);
    __builtin_amdgcn_s_setprio(0);
    asm volatile("s_barrier" ::: "memory");

    // ---- phase 2: i{2,3} x j{0,1}
    short8 a20 = rdA(2, 0), a21 = rdA(2, 1), a30 = rdA(3, 0), a31 = rdA(3, 1);
    if (do_stage) { stageA(bstage, 0, k2); stageA(bstage, 1, k2); }
    asm volatile("s_barrier" ::: "memory");
    __builtin_amdgcn_s_setprio(1);
    acc[2][0] = mfma16(a20, b00, acc[2][0]); acc[2][0] = mfma16(a21, b01, acc[2][0]);
    acc[2][1] = mfma16(a20, b10, acc[2][1]); acc[2][1] = mfma16(a21, b11, acc[2][1]);
    acc[3][0] = mfma16(a30, b00, acc[3][0]); acc[3][0] = mfma16(a31, b01, acc[3][0]);
    acc[3][1] = mfma16(a30, b10, acc[3][1]); acc[3][1] = mfma16(a31, b11, acc[3][1]);
    __builtin_amdgcn_s_setprio(0);
    asm volatile("s_barrier" ::: "memory");

    // ---- phase 3: i{2,3} x j{2,3}; counted-vmcnt gate for next tile
    if (do_stage)            asm volatile("s_waitcnt vmcnt(6)" ::: "memory");
    else if (t + 1 < nk)     asm volatile("s_waitcnt vmcnt(0)" ::: "memory");
    asm volatile("s_barrier" ::: "memory");
    __builtin_amdgcn_s_setprio(1);
    acc[2][2] = mfma16(a20, b20, acc[2][2]); acc[2][2] = mfma16(a21, b21, acc[2][2]);
    acc[2][3] = mfma16(a20, b30, acc[2][3]); acc[2][3] = mfma16(a21, b31, acc[2][3]);
    acc[3][2] = mfma16(a30, b20, acc[3][2]); acc[3][2] = mfma16(a31, b21, acc[3][2]);
    acc[3][3] = mfma16(a30, b30, acc[3][3]); acc[3][3] = mfma16(a31, b31, acc[3][3]);
    __builtin_amdgcn_s_setprio(0);
    asm volatile("s_barrier" ::: "memory");

    const int tmp = bcur; bcur = bnext; bnext = bstage; bstage = tmp;
  }

#pragma unroll
  for (int j = 0; j < 4; j++) {
    const int col = bn + wc + j * 16 + rr;
    const float bv = bias[col];
#pragma unroll
    for (int i = 0; i < 4; i++) {
#pragma unroll
      for (int q = 0; q < 4; q++) {
        const int row = bm + wr + i * 16 + sg * 4 + q;
        float v = acc[i][j][q] + bv;
        if constexpr (RESID) v += resid[(size_t)row * N + col];
        if constexpr (ACT == 1) v = gelu_exact(v);
        if constexpr (ACT == 2) v = v / (1.f + __expf(-v));
        if constexpr (sizeof(OutT) == 2) C[(size_t)row * N + col] = (OutT)f2bf(v);
        else C[(size_t)row * N + col] = v;
      }
    }
  }
}

template <int ACT, bool RESID, typename OutT>
__global__ __launch_bounds__(512) void gemm8_bt(
    const short* __restrict__ A, const short* __restrict__ Bt,
    const float* __restrict__ bias, const float* __restrict__ resid,
    OutT* __restrict__ C, int N, int K) {
  gemm8_core<ACT, RESID, OutT>(A, Bt, bias, resid, C, N, K);
}

__global__ __launch_bounds__(512) void gemm8_qkv_kernel(
    const short* __restrict__ A, const short* __restrict__ Wt3,
    const float* __restrict__ bq, const float* __restrict__ bk,
    const float* __restrict__ bv, short* __restrict__ outqkv) {
  const int z = blockIdx.z;
  const short* Bt = Wt3 + (size_t)z * NB_D * NB_D;
  const float* bias = (z == 0) ? bq : ((z == 1) ? bk : bv);
  short* C = outqkv + (size_t)z * NB_M * NB_D;
  gemm8_core<0, false, short>(A, Bt, bias, nullptr, C, NB_D, NB_D);
}

// ---------------------------------------------------------------------------
// Fused causal flash attention, bf16 MFMA (unchanged from round 1).
// ---------------------------------------------------------------------------
__global__ __launch_bounds__(256) void attn_kernel(
    const short* __restrict__ qkv, short* __restrict__ out) {
  const int qt = blockIdx.x, hh = blockIdx.y, bb = blockIdx.z;
  const int tid = threadIdx.x;
  const int w = tid >> 6, lane = tid & 63;
  const int rr = lane & 15, sg = lane >> 4;

  const size_t MD = (size_t)NB_M * NB_D;
  const short* Q = qkv;
  const short* K = qkv + MD;
  const short* V = qkv + 2 * MD;

  __shared__ short Ks[64][64];
  __shared__ short Vt[64][64];
  __shared__ short Ps[4][16][64];

  short8 qf[2];
  {
    const size_t qrow = (size_t)bb * NB_S + qt * 64 + w * 16 + rr;
#pragma unroll
    for (int ks = 0; ks < 2; ks++)
      qf[ks] = *(const short8*)&Q[qrow * NB_D + hh * 64 + ks * 32 + sg * 8];
  }

  float mrow[4], lrow[4];
  f32x4 o[4];
#pragma unroll
  for (int j = 0; j < 4; j++) { mrow[j] = -INFINITY; lrow[j] = 0.f; }
#pragma unroll
  for (int nb = 0; nb < 4; nb++) o[nb] = f32x4{0.f, 0.f, 0.f, 0.f};

  for (int kt = 0; kt <= qt; kt++) {
    __syncthreads();
    {
      const int p = lane & 7;
#pragma unroll
      for (int inst = 0; inst < 2; inst++) {
        const int r = w * 16 + inst * 8 + (lane >> 3);
        const int sl = p ^ (r & 7);
        load_lds16(K + ((size_t)bb * NB_S + kt * 64 + r) * NB_D + hh * 64 + sl * 8,
                   &Ks[w * 16 + inst * 8][0]);
      }
    }
    {
#pragma unroll
      for (int cc = 0; cc < 2; cc++) {
        const int c = tid * 2 + cc;
        const int sk = c >> 3, sl = c & 7;
        short8 vv = *(const short8*)&V[((size_t)bb * NB_S + kt * 64 + sk) * NB_D + hh * 64 + sl * 8];
        const int ss = sk >> 3;
#pragma unroll
        for (int j = 0; j < 8; j++) {
          const int dh = sl * 8 + j;
          Vt[dh][(ss ^ (dh & 7)) * 8 + (sk & 7)] = vv[j];
        }
      }
    }
    __syncthreads();

    f32x4 sf[4];
#pragma unroll
    for (int nb = 0; nb < 4; nb++) sf[nb] = f32x4{0.f, 0.f, 0.f, 0.f};
#pragma unroll
    for (int ks = 0; ks < 2; ks++) {
#pragma unroll
      for (int nb = 0; nb < 4; nb++) {
        const int ck = nb * 16 + rr;
        short8 kf = *(const short8*)&Ks[ck][((ks * 4 + sg) ^ (ck & 7)) * 8];
        sf[nb] = mfma16(qf[ks], kf, sf[nb]);
      }
    }
    const int rbase = qt * 64 + w * 16 + sg * 4;
    float pmax[4] = {-INFINITY, -INFINITY, -INFINITY, -INFINITY};
#pragma unroll
    for (int nb = 0; nb < 4; nb++) {
      const int cg = kt * 64 + nb * 16 + rr;
#pragma unroll
      for (int j = 0; j < 4; j++) {
        float sv = sf[nb][j] * 0.125f;
        if (cg > rbase + j) sv = -INFINITY;
        sf[nb][j] = sv;
        pmax[j] = fmaxf(pmax[j], sv);
      }
    }
#pragma unroll
    for (int o1 = 1; o1 < 16; o1 <<= 1)
#pragma unroll
      for (int j = 0; j < 4; j++)
        pmax[j] = fmaxf(pmax[j], __shfl_xor(pmax[j], o1, 64));

    float resc[4], psum[4];
#pragma unroll
    for (int j = 0; j < 4; j++) {
      const float mn = fmaxf(mrow[j], pmax[j]);
      resc[j] = __expf(mrow[j] - mn);
      mrow[j] = mn;
      psum[j] = 0.f;
    }
#pragma unroll
    for (int nb = 0; nb < 4; nb++)
#pragma unroll
      for (int j = 0; j < 4; j++) {
        const float p = __expf(sf[nb][j] - mrow[j]);
        sf[nb][j] = p;
        psum[j] += p;
      }
#pragma unroll
    for (int o1 = 1; o1 < 16; o1 <<= 1)
#pragma unroll
      for (int j = 0; j < 4; j++) psum[j] += __shfl_xor(psum[j], o1, 64);
#pragma unroll
    for (int j = 0; j < 4; j++) lrow[j] = lrow[j] * resc[j] + psum[j];
#pragma unroll
    for (int nb = 0; nb < 4; nb++)
#pragma unroll
      for (int j = 0; j < 4; j++) o[nb][j] *= resc[j];

#pragma unroll
    for (int nb = 0; nb < 4; nb++) {
      const int ck = nb * 16 + rr;
      const int ss = ck >> 3;
#pragma unroll
      for (int j = 0; j < 4; j++) {
        const int rq = sg * 4 + j;
        Ps[w][rq][(ss ^ (rq & 7)) * 8 + (ck & 7)] = f2bf(sf[nb][j]);
      }
    }
#pragma unroll
    for (int ks = 0; ks < 2; ks++) {
      short8 pf = *(const short8*)&Ps[w][rr][((ks * 4 + sg) ^ (rr & 7)) * 8];
#pragma unroll
      for (int nb = 0; nb < 4; nb++) {
        const int dh = nb * 16 + rr;
        short8 vf = *(const short8*)&Vt[dh][((ks * 4 + sg) ^ (dh & 7)) * 8];
        o[nb] = mfma16(pf, vf, o[nb]);
      }
    }
  }

  {
    const size_t orow0 = (size_t)bb * NB_S + qt * 64 + w * 16;
#pragma unroll
    for (int nb = 0; nb < 4; nb++)
#pragma unroll
      for (int j = 0; j < 4; j++) {
        const float v = o[nb][j] / lrow[j];
        out[(orow0 + sg * 4 + j) * NB_D + hh * 64 + nb * 16 + rr] = f2bf(v);
      }
  }
}

// ---------------------------------------------------------------------------
// Head stage 2: out(8176,30) = hbuf(.,100) @ Wh2(100,30) + bh2, fp32.
// Block = 8 token rows; hbuf rows LDS-staged; lanes c<30 compute.
// ---------------------------------------------------------------------------
__global__ __launch_bounds__(256) void head2_kernel(
    const float* __restrict__ hbuf, const float* __restrict__ Wh2,
    const float* __restrict__ bh2, float* __restrict__ outp) {
  __shared__ float hs[8][NB_HID];
  const int g0 = blockIdx.x * 8;
  for (int idx = threadIdx.x; idx < 8 * NB_HID; idx += 256) {
    const int r = idx / NB_HID, k = idx - r * NB_HID;
    const int gt = g0 + r;
    const int b = gt / NB_T, tt = gt - b * NB_T;
    hs[r][k] = hbuf[(size_t)(b * NB_S + 1 + tt) * 128 + k];
  }
  __syncthreads();
  const int r = threadIdx.x >> 5, c = threadIdx.x & 31;
  if (c < NB_OUT) {
    float acc = bh2[c];
#pragma unroll
    for (int k = 0; k < NB_HID; k++) acc += hs[r][k] * Wh2[k * NB_OUT + c];
    outp[(size_t)(g0 + r) * NB_OUT + c] = acc;
  }
}

// ---------------------------------------------------------------------------
extern "C" void kernel_launch(void* const* d_in, const int* in_sizes, int n_in,
                              void* d_out, int out_size, void* d_ws, size_t ws_size,
                              hipStream_t stream) {
  const float* states = (const float*)d_in[0];
  const float* goals  = (const float*)d_in[1];
  const float* Wtok   = (const float*)d_in[2];
  const float* btok   = (const float*)d_in[3];
  const float* pos    = (const float*)d_in[4];
  const float* ln1_g  = (const float*)d_in[5];
  const float* ln1_b  = (const float*)d_in[6];
  const float* Wq     = (const float*)d_in[7];
  const float* bq     = (const float*)d_in[8];
  const float* Wk     = (const float*)d_in[9];
  const float* bk     = (const float*)d_in[10];
  const float* Wv     = (const float*)d_in[11];
  const float* bv     = (const float*)d_in[12];
  const float* Wp     = (const float*)d_in[13];
  const float* bp     = (const float*)d_in[14];
  const float* ln2_g  = (const float*)d_in[15];
  const float* ln2_b  = (const float*)d_in[16];
  const float* Wm1    = (const float*)d_in[17];
  const float* bm1    = (const float*)d_in[18];
  const float* Wm2    = (const float*)d_in[19];
  const float* bm2    = (const float*)d_in[20];
  const float* lnf_g  = (const float*)d_in[21];
  const float* lnf_b  = (const float*)d_in[22];
  const float* Wh1    = (const float*)d_in[23];
  const float* bh1    = (const float*)d_in[24];
  const float* Wh2    = (const float*)d_in[25];
  const float* bh2    = (const float*)d_in[26];

  char* wsp = (char*)d_ws;
  size_t off = 0;
  auto carve = [&](size_t bytes) -> char* {
    char* p = wsp + off;
    off += (bytes + 1023) & ~(size_t)1023;
    return p;
  };
  short* Wqkv_t = (short*)carve((size_t)NB_L * 3 * NB_D * NB_D * 2);
  short* Wp_t   = (short*)carve((size_t)NB_L * NB_D * NB_D * 2);
  short* Wm1_t  = (short*)carve((size_t)NB_L * NB_DFF * NB_D * 2);
  short* Wm2_t  = (short*)carve((size_t)NB_L * NB_D * NB_DFF * 2);
  float* x      = (float*)carve((size_t)NB_M * NB_D * 4);
  short* h      = (short*)carve((size_t)NB_M * NB_D * 2);
  short* qkvb   = (short*)carve((size_t)3 * NB_M * NB_D * 2);
  short* mlp    = (short*)carve((size_t)NB_M * NB_DFF * 2);
  short* Wh1t   = (short*)carve((size_t)128 * NB_D * 2);
  float* bh1p   = (float*)carve(128 * 4);
  short* attout = mlp;           // alias: dead before mlp is written
  float* hbuf   = (float*)qkvb;  // alias: qkv dead after last attention

  const dim3 thr(256), thr8(512);
  const size_t DD = (size_t)NB_D * NB_D;
  const size_t DF = (size_t)NB_D * NB_DFF;

  tconv_kernel<<<dim3(32, 32, NB_L), thr, 0, stream>>>(Wq, Wqkv_t + 0 * DD, NB_D, NB_D, DD, 3 * DD);
  tconv_kernel<<<dim3(32, 32, NB_L), thr, 0, stream>>>(Wk, Wqkv_t + 1 * DD, NB_D, NB_D, DD, 3 * DD);
  tconv_kernel<<<dim3(32, 32, NB_L), thr, 0, stream>>>(Wv, Wqkv_t + 2 * DD, NB_D, NB_D, DD, 3 * DD);
  tconv_kernel<<<dim3(32, 32, NB_L), thr, 0, stream>>>(Wp, Wp_t, NB_D, NB_D, DD, DD);
  tconv_kernel<<<dim3(128, 32, NB_L), thr, 0, stream>>>(Wm1, Wm1_t, NB_D, NB_DFF, DF, DF);
  tconv_kernel<<<dim3(32, 128, NB_L), thr, 0, stream>>>(Wm2, Wm2_t, NB_DFF, NB_D, DF, DF);
  whead_prep<<<512, thr, 0, stream>>>(Wh1, bh1, Wh1t, bh1p);

  embed_kernel<<<NB_M, thr, 0, stream>>>(states, goals, Wtok, btok, pos, x);

  for (int l = 0; l < NB_L; l++) {
    ln_kernel<short><<<NB_M, thr, 0, stream>>>(x, ln1_g + l * NB_D, ln1_b + l * NB_D, h);
    gemm8_qkv_kernel<<<dim3(NB_D / 256, NB_M / 128, 3), thr8, 0, stream>>>(
        h, Wqkv_t + (size_t)l * 3 * DD, bq + l * NB_D, bk + l * NB_D, bv + l * NB_D, qkvb);
    attn_kernel<<<dim3(NB_S / 64, NB_H, NB_B), thr, 0, stream>>>(qkvb, attout);
    gemm8_bt<0, true, float><<<dim3(NB_D / 256, NB_M / 128), thr8, 0, stream>>>(
        attout, Wp_t + (size_t)l * DD, bp + l * NB_D, x, x, NB_D, NB_D);
    ln_kernel<short><<<NB_M, thr, 0, stream>>>(x, ln2_g + l * NB_D, ln2_b + l * NB_D, h);
    gemm8_bt<1, false, short><<<dim3(NB_DFF / 256, NB_M / 128), thr8, 0, stream>>>(
        h, Wm1_t + (size_t)l * DF, bm1 + l * NB_DFF, nullptr, mlp, NB_DFF, NB_D);
    gemm8_bt<0, true, float><<<dim3(NB_D / 256, NB_M / 128), thr8, 0, stream>>>(
        mlp, Wm2_t + (size_t)l * DF, bm2 + l * NB_D, x, x, NB_D, NB_DFF);
  }

  ln_kernel<short><<<NB_M, thr, 0, stream>>>(x, lnf_g, lnf_b, h);
  gemm_bt<2, false, float><<<dim3(1, NB_M / 128), thr, 0, stream>>>(
      h, Wh1t, bh1p, nullptr, hbuf, 128, NB_D);
  head2_kernel<<<NB_M / 8, thr, 0, stream>>>(hbuf, Wh2, bh2, (float*)d_out);
}

// Round 3
// 3156.747 us; speedup vs baseline: 1.2536x; 1.0724x over previous
//
#include <hip/hip_runtime.h>
#include <cstdint>
#include <math.h>

#define NB_B   16
#define NB_T   511
#define NB_S   512
#define NB_OBS 60
#define NB_D   1024
#define NB_H   16
#define NB_L   8
#define NB_DFF 4096
#define NB_HID 100
#define NB_OUT 30
#define NB_M   8192   // B*S rows

typedef __attribute__((ext_vector_type(8))) short  short8;
typedef __attribute__((ext_vector_type(4))) short  short4v;
typedef __attribute__((ext_vector_type(4))) float  f32x4;
typedef __attribute__((ext_vector_type(8))) __bf16 bf16x8;

template <int N_> struct ic { static constexpr int v = N_; };

__device__ __forceinline__ short f2bf(float f) {
  union { float f; unsigned u; } a; a.f = f;
  unsigned u = a.u + 0x7fffu + ((a.u >> 16) & 1u);   // RTNE
  return (short)(u >> 16);
}

__device__ __forceinline__ void load_lds16(const void* g, void* l) {
  __builtin_amdgcn_global_load_lds(
      (__attribute__((address_space(1))) unsigned int*)(uintptr_t)g,
      (__attribute__((address_space(3))) unsigned int*)(unsigned)(uintptr_t)l,
      16, 0, 0);
}

__device__ __forceinline__ f32x4 mfma16(short8 a, short8 b, f32x4 c) {
  return __builtin_amdgcn_mfma_f32_16x16x32_bf16(
      __builtin_bit_cast(bf16x8, a), __builtin_bit_cast(bf16x8, b), c, 0, 0, 0);
}

__device__ __forceinline__ float gelu_exact(float v) {
  return 0.5f * v * (1.f + erff(v * 0.70710678118654752f));
}

// ---------------------------------------------------------------------------
// Weight transpose + fp32->bf16 convert: src (R,C) fp32 -> dst (C,R) bf16 bits
// ---------------------------------------------------------------------------
__global__ __launch_bounds__(256) void tconv_kernel(
    const float* __restrict__ src, short* __restrict__ dst,
    int R, int C, size_t sstride, size_t dstride) {
  __shared__ float t[32][33];
  const float* s0 = src + blockIdx.z * sstride;
  short* d0 = dst + blockIdx.z * dstride;
  const int c0 = blockIdx.x * 32, r0 = blockIdx.y * 32;
  const int tx = threadIdx.x & 31, ty = threadIdx.x >> 5;
#pragma unroll
  for (int i = 0; i < 4; i++)
    t[ty + 8 * i][tx] = s0[(size_t)(r0 + ty + 8 * i) * C + c0 + tx];
  __syncthreads();
#pragma unroll
  for (int i = 0; i < 4; i++)
    d0[(size_t)(c0 + ty + 8 * i) * R + r0 + tx] = f2bf(t[tx][ty + 8 * i]);
}

// ---------------------------------------------------------------------------
// Head weight prep: Wh1 (1024,100) fp32 -> Wh1t (128,1024) bf16 (zero-padded),
// bh1 (100) -> bh1p (128) fp32 zero-padded.
// ---------------------------------------------------------------------------
__global__ __launch_bounds__(256) void whead_prep(
    const float* __restrict__ Wh1, const float* __restrict__ bh1,
    short* __restrict__ Wh1t, float* __restrict__ bh1p) {
  const int idx = blockIdx.x * 256 + threadIdx.x;   // 0 .. 128*1024-1
  const int n = idx >> 10, k = idx & 1023;
  Wh1t[idx] = (n < NB_HID) ? f2bf(Wh1[k * NB_HID + n]) : (short)0;
  if (idx < 128) bh1p[idx] = (idx < NB_HID) ? bh1[idx] : 0.f;
}

// ---------------------------------------------------------------------------
// Token + positional embedding -> x fp32 (M, D)
// ---------------------------------------------------------------------------
__global__ __launch_bounds__(256) void embed_kernel(
    const float* __restrict__ states, const float* __restrict__ goals,
    const float* __restrict__ Wtok, const float* __restrict__ btok,
    const float* __restrict__ pos, float* __restrict__ x) {
  const int row = blockIdx.x;              // b*512 + s
  const int b = row >> 9, s = row & (NB_S - 1);
  __shared__ float tok[NB_OBS];
  if (threadIdx.x < NB_OBS)
    tok[threadIdx.x] = (s == 0)
        ? goals[b * NB_OBS + threadIdx.x]
        : states[((size_t)b * NB_T + (s - 1)) * NB_OBS + threadIdx.x];
  __syncthreads();
#pragma unroll
  for (int i = 0; i < 4; i++) {
    const int d = threadIdx.x + i * 256;
    float acc = btok[d] + pos[(size_t)s * NB_D + d];
    for (int o = 0; o < NB_OBS; o++) acc += tok[o] * Wtok[o * NB_D + d];
    x[(size_t)row * NB_D + d] = acc;
  }
}

// ---------------------------------------------------------------------------
// LayerNorm: fp32 (rows, D) -> OutT (short=bf16 bits, or float)
// ---------------------------------------------------------------------------
template <typename OutT>
__global__ __launch_bounds__(256) void ln_kernel(
    const float* __restrict__ xin, const float* __restrict__ gam,
    const float* __restrict__ bet, OutT* __restrict__ outp) {
  const int row = blockIdx.x;
  const int tid = threadIdx.x;
  const float4 v = ((const float4*)(xin + (size_t)row * NB_D))[tid];
  float s = v.x + v.y + v.z + v.w;
  float s2 = v.x * v.x + v.y * v.y + v.z * v.z + v.w * v.w;
#pragma unroll
  for (int o = 32; o; o >>= 1) {
    s += __shfl_down(s, o, 64);
    s2 += __shfl_down(s2, o, 64);
  }
  __shared__ float red[8];
  if ((tid & 63) == 0) { red[tid >> 6] = s; red[4 + (tid >> 6)] = s2; }
  __syncthreads();
  const float S1 = red[0] + red[1] + red[2] + red[3];
  const float S2 = red[4] + red[5] + red[6] + red[7];
  const float mean = S1 * (1.f / NB_D);
  const float var = S2 * (1.f / NB_D) - mean * mean;
  const float rs = rsqrtf(var + 1e-5f);
  const float4 g4 = ((const float4*)gam)[tid];
  const float4 b4 = ((const float4*)bet)[tid];
  const float o0 = (v.x - mean) * rs * g4.x + b4.x;
  const float o1 = (v.y - mean) * rs * g4.y + b4.y;
  const float o2 = (v.z - mean) * rs * g4.z + b4.z;
  const float o3 = (v.w - mean) * rs * g4.w + b4.w;
  if constexpr (sizeof(OutT) == 2) {
    short4v r = {f2bf(o0), f2bf(o1), f2bf(o2), f2bf(o3)};
    *(short4v*)((short*)outp + (size_t)row * NB_D + tid * 4) = r;
  } else {
    ((float4*)((float*)outp + (size_t)row * NB_D))[tid] = make_float4(o0, o1, o2, o3);
  }
}

// ---------------------------------------------------------------------------
// OLD m97-style 128x128 GEMM core (kept for the head GEMM, N=128).
// ---------------------------------------------------------------------------
template <int ACT, bool RESID, typename OutT>
__global__ __launch_bounds__(256) void gemm_bt(
    const short* __restrict__ A, const short* __restrict__ Bt,
    const float* __restrict__ bias, const float* __restrict__ resid,
    OutT* __restrict__ C, int N, int K) {
  __shared__ short As[128][32];
  __shared__ short Bs[128][32];
  const int bm = blockIdx.y * 128, bn = blockIdx.x * 128;
  const int tid = threadIdx.x;
  const int w = tid >> 6, lane = tid & 63;
  const int wr = (w >> 1) * 64, wc = (w & 1) * 64;
  const int rr = lane & 15, sg = lane >> 4;

  f32x4 acc[4][4];
#pragma unroll
  for (int i = 0; i < 4; i++)
#pragma unroll
    for (int j = 0; j < 4; j++) acc[i][j] = f32x4{0.f, 0.f, 0.f, 0.f};

  const int srow0 = w * 32 + (lane >> 2);
  const int sslot = lane & 3;

  for (int k0 = 0; k0 < K; k0 += 32) {
    __syncthreads();
#pragma unroll
    for (int inst = 0; inst < 2; inst++) {
      const int r = srow0 + inst * 16;
      const int sl = sslot ^ ((r >> 1) & 3);
      load_lds16(A + (size_t)(bm + r) * K + k0 + sl * 8, &As[w * 32 + inst * 16][0]);
      load_lds16(Bt + (size_t)(bn + r) * K + k0 + sl * 8, &Bs[w * 32 + inst * 16][0]);
    }
    __syncthreads();
    short8 a[4], b[4];
#pragma unroll
    for (int i = 0; i < 4; i++) {
      const int r = wr + i * 16 + rr;
      a[i] = *(const short8*)&As[r][(sg ^ ((r >> 1) & 3)) * 8];
      const int c = wc + i * 16 + rr;
      b[i] = *(const short8*)&Bs[c][(sg ^ ((c >> 1) & 3)) * 8];
    }
#pragma unroll
    for (int i = 0; i < 4; i++)
#pragma unroll
      for (int j = 0; j < 4; j++) acc[i][j] = mfma16(a[i], b[j], acc[i][j]);
  }

#pragma unroll
  for (int j = 0; j < 4; j++) {
    const int col = bn + wc + j * 16 + rr;
    const float bv = bias[col];
#pragma unroll
    for (int i = 0; i < 4; i++) {
#pragma unroll
      for (int q = 0; q < 4; q++) {
        const int row = bm + wr + i * 16 + sg * 4 + q;
        float v = acc[i][j][q] + bv;
        if constexpr (RESID) v += resid[(size_t)row * N + col];
        if constexpr (ACT == 1) v = gelu_exact(v);
        if constexpr (ACT == 2) v = v / (1.f + __expf(-v));
        if constexpr (sizeof(OutT) == 2) C[(size_t)row * N + col] = (OutT)f2bf(v);
        else C[(size_t)row * N + col] = v;
      }
    }
  }
}

// ---------------------------------------------------------------------------
// Phase-pipelined GEMM v2: BM=128, BN=256, BK=64, 512 threads (8 waves 2Mx4N,
// 64x64/wave). 3 rotating LDS K-tile buffers (144 KiB), prefetch depth 2,
// counted vmcnt(6). K templated -> K-loop unrolled x3 so buffer indices are
// compile-time (ds_read = base + imm; lane-constant swizzled offsets hoisted).
// 2 fat phases/K-tile (16 MFMA each). T1 bijective XCD swizzle on the grid.
// ---------------------------------------------------------------------------
template <int K, int ACT, bool RESID, typename OutT>
__device__ __forceinline__ void gemm8_core(
    const short* __restrict__ A, const short* __restrict__ Bt,
    const float* __restrict__ bias, const float* __restrict__ resid,
    OutT* __restrict__ C, int N) {
  constexpr int NK = K / 64;
  __shared__ short As[3][128 * 64];   // 48 KiB
  __shared__ short Bs[3][256 * 64];   // 96 KiB

  // T1: bijective XCD swizzle (nwg % 8 == 0 for all shapes here)
  const int gx = N >> 8;
  int wg = blockIdx.x + gx * blockIdx.y;
  {
    const int q = (gx * (NB_M / 128)) >> 3;
    wg = (wg & 7) * q + (wg >> 3);
  }
  const int bm = (wg / gx) * 128, bn = (wg % gx) * 256;

  const int tid = threadIdx.x;
  const int w = tid >> 6, lane = tid & 63;
  const int wr = (w >> 2) * 64, wc = (w & 3) * 64;
  const int rr = lane & 15, sg = lane >> 4;
  const int lrow = lane >> 3;
  const int lslot = (lane & 7) ^ lrow;     // pre-swizzled global source slot

  const short* Asrc = A + (size_t)(bm + w * 8 + lrow) * K + lslot * 8;
  const short* Bsrc = Bt + (size_t)(bn + w * 8 + lrow) * K + lslot * 8;
  short* Adst = &As[0][(w * 8) * 64];      // +SBUF*8192, +chunk*4096
  short* Bdst = &Bs[0][(w * 8) * 64];      // +SBUF*16384, +chunk*4096

  // lane-constant LDS read offsets (shorts), valid for every K-tile
  const int ar = wr + rr, br = wc + rr;
  const int aoff0 = ar * 64 + ((0 + sg) ^ (ar & 7)) * 8;
  const int aoff1 = ar * 64 + ((4 + sg) ^ (ar & 7)) * 8;
  const int boff0 = br * 64 + ((0 + sg) ^ (br & 7)) * 8;
  const int boff1 = br * 64 + ((4 + sg) ^ (br & 7)) * 8;

  f32x4 acc[4][4];
#pragma unroll
  for (int i = 0; i < 4; i++)
#pragma unroll
    for (int j = 0; j < 4; j++) acc[i][j] = f32x4{0.f, 0.f, 0.f, 0.f};

  auto stage_tile = [&](int sb, int k0) {
    load_lds16(Bsrc + k0,                      Bdst + sb * 16384);
    load_lds16(Bsrc + (size_t)64 * K + k0,     Bdst + sb * 16384 + 4096);
    load_lds16(Bsrc + (size_t)128 * K + k0,    Bdst + sb * 16384 + 8192);
    load_lds16(Bsrc + (size_t)192 * K + k0,    Bdst + sb * 16384 + 12288);
    load_lds16(Asrc + k0,                      Adst + sb * 8192);
    load_lds16(Asrc + (size_t)64 * K + k0,     Adst + sb * 8192 + 4096);
  };

  stage_tile(0, 0);
  stage_tile(1, 64);
  asm volatile("s_waitcnt vmcnt(6)" ::: "memory");
  __builtin_amdgcn_s_barrier();

  auto ktile = [&](auto BUFC, auto SBUFC, int t) {
    constexpr int BUF = decltype(BUFC)::v;
    constexpr int SBUF = decltype(SBUFC)::v;
    const bool ds = (t + 2 < NK);
    const int k2 = (t + 2) * 64;
    const short* Ab = As[BUF];
    const short* Bb = Bs[BUF];

    // ---- phase 0: read a0x,a1x + all B; stage 4 B chunks
    short8 a00 = *(const short8*)(Ab + aoff0);
    short8 a01 = *(const short8*)(Ab + aoff1);
    short8 a10 = *(const short8*)(Ab + aoff0 + 1024);
    short8 a11 = *(const short8*)(Ab + aoff1 + 1024);
    short8 b00 = *(const short8*)(Bb + boff0);
    short8 b01 = *(const short8*)(Bb + boff1);
    short8 b10 = *(const short8*)(Bb + boff0 + 1024);
    short8 b11 = *(const short8*)(Bb + boff1 + 1024);
    short8 b20 = *(const short8*)(Bb + boff0 + 2048);
    short8 b21 = *(const short8*)(Bb + boff1 + 2048);
    short8 b30 = *(const short8*)(Bb + boff0 + 3072);
    short8 b31 = *(const short8*)(Bb + boff1 + 3072);
    if (ds) {
      load_lds16(Bsrc + k2,                   Bdst + SBUF * 16384);
      load_lds16(Bsrc + (size_t)64 * K + k2,  Bdst + SBUF * 16384 + 4096);
      load_lds16(Bsrc + (size_t)128 * K + k2, Bdst + SBUF * 16384 + 8192);
      load_lds16(Bsrc + (size_t)192 * K + k2, Bdst + SBUF * 16384 + 12288);
    }
    __builtin_amdgcn_s_barrier();
    asm volatile("s_waitcnt lgkmcnt(0)" ::: "memory");
    __builtin_amdgcn_s_setprio(1);
    acc[0][0] = mfma16(a00, b00, acc[0][0]);
    acc[0][1] = mfma16(a00, b10, acc[0][1]);
    acc[0][2] = mfma16(a00, b20, acc[0][2]);
    acc[0][3] = mfma16(a00, b30, acc[0][3]);
    acc[1][0] = mfma16(a10, b00, acc[1][0]);
    acc[1][1] = mfma16(a10, b10, acc[1][1]);
    acc[1][2] = mfma16(a10, b20, acc[1][2]);
    acc[1][3] = mfma16(a10, b30, acc[1][3]);
    acc[0][0] = mfma16(a01, b01, acc[0][0]);
    acc[0][1] = mfma16(a01, b11, acc[0][1]);
    acc[0][2] = mfma16(a01, b21, acc[0][2]);
    acc[0][3] = mfma16(a01, b31, acc[0][3]);
    acc[1][0] = mfma16(a11, b01, acc[1][0]);
    acc[1][1] = mfma16(a11, b11, acc[1][1]);
    acc[1][2] = mfma16(a11, b21, acc[1][2]);
    acc[1][3] = mfma16(a11, b31, acc[1][3]);
    __builtin_amdgcn_s_setprio(0);
    __builtin_amdgcn_s_barrier();

    // ---- phase 1: read a2x,a3x; stage 2 A chunks; MFMA; vmcnt gate
    short8 a20 = *(const short8*)(Ab + aoff0 + 2048);
    short8 a21 = *(const short8*)(Ab + aoff1 + 2048);
    short8 a30 = *(const short8*)(Ab + aoff0 + 3072);
    short8 a31 = *(const short8*)(Ab + aoff1 + 3072);
    if (ds) {
      load_lds16(Asrc + k2,                  Adst + SBUF * 8192);
      load_lds16(Asrc + (size_t)64 * K + k2, Adst + SBUF * 8192 + 4096);
    }
    __builtin_amdgcn_s_barrier();
    asm volatile("s_waitcnt lgkmcnt(0)" ::: "memory");
    __builtin_amdgcn_s_setprio(1);
    acc[2][0] = mfma16(a20, b00, acc[2][0]);
    acc[2][1] = mfma16(a20, b10, acc[2][1]);
    acc[2][2] = mfma16(a20, b20, acc[2][2]);
    acc[2][3] = mfma16(a20, b30, acc[2][3]);
    acc[3][0] = mfma16(a30, b00, acc[3][0]);
    acc[3][1] = mfma16(a30, b10, acc[3][1]);
    acc[3][2] = mfma16(a30, b20, acc[3][2]);
    acc[3][3] = mfma16(a30, b30, acc[3][3]);
    acc[2][0] = mfma16(a21, b01, acc[2][0]);
    acc[2][1] = mfma16(a21, b11, acc[2][1]);
    acc[2][2] = mfma16(a21, b21, acc[2][2]);
    acc[2][3] = mfma16(a21, b31, acc[2][3]);
    acc[3][0] = mfma16(a31, b01, acc[3][0]);
    acc[3][1] = mfma16(a31, b11, acc[3][1]);
    acc[3][2] = mfma16(a31, b21, acc[3][2]);
    acc[3][3] = mfma16(a31, b31, acc[3][3]);
    __builtin_amdgcn_s_setprio(0);
    // gate: next tile's buffer (staged one tile ago) must be landed before
    // any wave crosses the final barrier and reads it.
    if (ds)              asm volatile("s_waitcnt vmcnt(6)" ::: "memory");
    else if (t + 1 < NK) asm volatile("s_waitcnt vmcnt(0)" ::: "memory");
    __builtin_amdgcn_s_barrier();
  };

  int t = 0;
#pragma unroll 1
  for (; t + 3 <= NK; t += 3) {
    ktile(ic<0>{}, ic<2>{}, t);
    ktile(ic<1>{}, ic<0>{}, t + 1);
    ktile(ic<2>{}, ic<1>{}, t + 2);
  }
  if constexpr (NK % 3 >= 1) ktile(ic<0>{}, ic<2>{}, NK - NK % 3);
  if constexpr (NK % 3 >= 2) ktile(ic<1>{}, ic<0>{}, NK - NK % 3 + 1);

  // epilogue
  const int col0 = bn + wc + rr;
  const float bv0 = bias[col0];
  const float bv1 = bias[col0 + 16];
  const float bv2 = bias[col0 + 32];
  const float bv3 = bias[col0 + 48];
#pragma unroll
  for (int i = 0; i < 4; i++) {
#pragma unroll
    for (int q = 0; q < 4; q++) {
      const size_t row = bm + wr + i * 16 + sg * 4 + q;
      float v0 = acc[i][0][q] + bv0;
      float v1 = acc[i][1][q] + bv1;
      float v2 = acc[i][2][q] + bv2;
      float v3 = acc[i][3][q] + bv3;
      if constexpr (RESID) {
        const float* rrow = resid + row * N + col0;
        v0 += rrow[0]; v1 += rrow[16]; v2 += rrow[32]; v3 += rrow[48];
      }
      if constexpr (ACT == 1) {
        v0 = gelu_exact(v0); v1 = gelu_exact(v1);
        v2 = gelu_exact(v2); v3 = gelu_exact(v3);
      }
      OutT* crow = C + row * N + col0;
      if constexpr (sizeof(OutT) == 2) {
        crow[0] = (OutT)f2bf(v0); crow[16] = (OutT)f2bf(v1);
        crow[32] = (OutT)f2bf(v2); crow[48] = (OutT)f2bf(v3);
      } else {
        crow[0] = v0; crow[16] = v1; crow[32] = v2; crow[48] = v3;
      }
    }
  }
}

template <int K, int ACT, bool RESID, typename OutT>
__global__ __launch_bounds__(512) void gemm8(
    const short* __restrict__ A, const short* __restrict__ Bt,
    const float* __restrict__ bias, const float* __restrict__ resid,
    OutT* __restrict__ C, int N) {
  gemm8_core<K, ACT, RESID, OutT>(A, Bt, bias, resid, C, N);
}

__global__ __launch_bounds__(512) void gemm8_qkv_kernel(
    const short* __restrict__ A, const short* __restrict__ Wt3,
    const float* __restrict__ bq, const float* __restrict__ bk,
    const float* __restrict__ bv, short* __restrict__ outqkv) {
  const int z = blockIdx.z;
  const short* Bt = Wt3 + (size_t)z * NB_D * NB_D;
  const float* bias = (z == 0) ? bq : ((z == 1) ? bk : bv);
  short* C = outqkv + (size_t)z * NB_M * NB_D;
  gemm8_core<NB_D, 0, false, short>(A, Bt, bias, nullptr, C, NB_D);
}

// ---------------------------------------------------------------------------
// Fused causal flash attention, bf16 MFMA (unchanged).
// ---------------------------------------------------------------------------
__global__ __launch_bounds__(256) void attn_kernel(
    const short* __restrict__ qkv, short* __restrict__ out) {
  const int qt = blockIdx.x, hh = blockIdx.y, bb = blockIdx.z;
  const int tid = threadIdx.x;
  const int w = tid >> 6, lane = tid & 63;
  const int rr = lane & 15, sg = lane >> 4;

  const size_t MD = (size_t)NB_M * NB_D;
  const short* Q = qkv;
  const short* K = qkv + MD;
  const short* V = qkv + 2 * MD;

  __shared__ short Ks[64][64];
  __shared__ short Vt[64][64];
  __shared__ short Ps[4][16][64];

  short8 qf[2];
  {
    const size_t qrow = (size_t)bb * NB_S + qt * 64 + w * 16 + rr;
#pragma unroll
    for (int ks = 0; ks < 2; ks++)
      qf[ks] = *(const short8*)&Q[qrow * NB_D + hh * 64 + ks * 32 + sg * 8];
  }

  float mrow[4], lrow[4];
  f32x4 o[4];
#pragma unroll
  for (int j = 0; j < 4; j++) { mrow[j] = -INFINITY; lrow[j] = 0.f; }
#pragma unroll
  for (int nb = 0; nb < 4; nb++) o[nb] = f32x4{0.f, 0.f, 0.f, 0.f};

  for (int kt = 0; kt <= qt; kt++) {
    __syncthreads();
    {
      const int p = lane & 7;
#pragma unroll
      for (int inst = 0; inst < 2; inst++) {
        const int r = w * 16 + inst * 8 + (lane >> 3);
        const int sl = p ^ (r & 7);
        load_lds16(K + ((size_t)bb * NB_S + kt * 64 + r) * NB_D + hh * 64 + sl * 8,
                   &Ks[w * 16 + inst * 8][0]);
      }
    }
    {
#pragma unroll
      for (int cc = 0; cc < 2; cc++) {
        const int c = tid * 2 + cc;
        const int sk = c >> 3, sl = c & 7;
        short8 vv = *(const short8*)&V[((size_t)bb * NB_S + kt * 64 + sk) * NB_D + hh * 64 + sl * 8];
        const int ss = sk >> 3;
#pragma unroll
        for (int j = 0; j < 8; j++) {
          const int dh = sl * 8 + j;
          Vt[dh][(ss ^ (dh & 7)) * 8 + (sk & 7)] = vv[j];
        }
      }
    }
    __syncthreads();

    f32x4 sf[4];
#pragma unroll
    for (int nb = 0; nb < 4; nb++) sf[nb] = f32x4{0.f, 0.f, 0.f, 0.f};
#pragma unroll
    for (int ks = 0; ks < 2; ks++) {
#pragma unroll
      for (int nb = 0; nb < 4; nb++) {
        const int ck = nb * 16 + rr;
        short8 kf = *(const short8*)&Ks[ck][((ks * 4 + sg) ^ (ck & 7)) * 8];
        sf[nb] = mfma16(qf[ks], kf, sf[nb]);
      }
    }
    const int rbase = qt * 64 + w * 16 + sg * 4;
    float pmax[4] = {-INFINITY, -INFINITY, -INFINITY, -INFINITY};
#pragma unroll
    for (int nb = 0; nb < 4; nb++) {
      const int cg = kt * 64 + nb * 16 + rr;
#pragma unroll
      for (int j = 0; j < 4; j++) {
        float sv = sf[nb][j] * 0.125f;
        if (cg > rbase + j) sv = -INFINITY;
        sf[nb][j] = sv;
        pmax[j] = fmaxf(pmax[j], sv);
      }
    }
#pragma unroll
    for (int o1 = 1; o1 < 16; o1 <<= 1)
#pragma unroll
      for (int j = 0; j < 4; j++)
        pmax[j] = fmaxf(pmax[j], __shfl_xor(pmax[j], o1, 64));

    float resc[4], psum[4];
#pragma unroll
    for (int j = 0; j < 4; j++) {
      const float mn = fmaxf(mrow[j], pmax[j]);
      resc[j] = __expf(mrow[j] - mn);
      mrow[j] = mn;
      psum[j] = 0.f;
    }
#pragma unroll
    for (int nb = 0; nb < 4; nb++)
#pragma unroll
      for (int j = 0; j < 4; j++) {
        const float p = __expf(sf[nb][j] - mrow[j]);
        sf[nb][j] = p;
        psum[j] += p;
      }
#pragma unroll
    for (int o1 = 1; o1 < 16; o1 <<= 1)
#pragma unroll
      for (int j = 0; j < 4; j++) psum[j] += __shfl_xor(psum[j], o1, 64);
#pragma unroll
    for (int j = 0; j < 4; j++) lrow[j] = lrow[j] * resc[j] + psum[j];
#pragma unroll
    for (int nb = 0; nb < 4; nb++)
#pragma unroll
      for (int j = 0; j < 4; j++) o[nb][j] *= resc[j];

#pragma unroll
    for (int nb = 0; nb < 4; nb++) {
      const int ck = nb * 16 + rr;
      const int ss = ck >> 3;
#pragma unroll
      for (int j = 0; j < 4; j++) {
        const int rq = sg * 4 + j;
        Ps[w][rq][(ss ^ (rq & 7)) * 8 + (ck & 7)] = f2bf(sf[nb][j]);
      }
    }
#pragma unroll
    for (int ks = 0; ks < 2; ks++) {
      short8 pf = *(const short8*)&Ps[w][rr][((ks * 4 + sg) ^ (rr & 7)) * 8];
#pragma unroll
      for (int nb = 0; nb < 4; nb++) {
        const int dh = nb * 16 + rr;
        short8 vf = *(const short8*)&Vt[dh][((ks * 4 + sg) ^ (dh & 7)) * 8];
        o[nb] = mfma16(pf, vf, o[nb]);
      }
    }
  }

  {
    const size_t orow0 = (size_t)bb * NB_S + qt * 64 + w * 16;
#pragma unroll
    for (int nb = 0; nb < 4; nb++)
#pragma unroll
      for (int j = 0; j < 4; j++) {
        const float v = o[nb][j] / lrow[j];
        out[(orow0 + sg * 4 + j) * NB_D + hh * 64 + nb * 16 + rr] = f2bf(v);
      }
  }
}

// ---------------------------------------------------------------------------
// Head stage 2: out(8176,30) = hbuf(.,100) @ Wh2(100,30) + bh2, fp32.
// ---------------------------------------------------------------------------
__global__ __launch_bounds__(256) void head2_kernel(
    const float* __restrict__ hbuf, const float* __restrict__ Wh2,
    const float* __restrict__ bh2, float* __restrict__ outp) {
  __shared__ float hs[8][NB_HID];
  const int g0 = blockIdx.x * 8;
  for (int idx = threadIdx.x; idx < 8 * NB_HID; idx += 256) {
    const int r = idx / NB_HID, k = idx - r * NB_HID;
    const int gt = g0 + r;
    const int b = gt / NB_T, tt = gt - b * NB_T;
    hs[r][k] = hbuf[(size_t)(b * NB_S + 1 + tt) * 128 + k];
  }
  __syncthreads();
  const int r = threadIdx.x >> 5, c = threadIdx.x & 31;
  if (c < NB_OUT) {
    float acc = bh2[c];
#pragma unroll
    for (int k = 0; k < NB_HID; k++) acc += hs[r][k] * Wh2[k * NB_OUT + c];
    outp[(size_t)(g0 + r) * NB_OUT + c] = acc;
  }
}

// ---------------------------------------------------------------------------
extern "C" void kernel_launch(void* const* d_in, const int* in_sizes, int n_in,
                              void* d_out, int out_size, void* d_ws, size_t ws_size,
                              hipStream_t stream) {
  const float* states = (const float*)d_in[0];
  const float* goals  = (const float*)d_in[1];
  const float* Wtok   = (const float*)d_in[2];
  const float* btok   = (const float*)d_in[3];
  const float* pos    = (const float*)d_in[4];
  const float* ln1_g  = (const float*)d_in[5];
  const float* ln1_b  = (const float*)d_in[6];
  const float* Wq     = (const float*)d_in[7];
  const float* bq     = (const float*)d_in[8];
  const float* Wk     = (const float*)d_in[9];
  const float* bk     = (const float*)d_in[10];
  const float* Wv     = (const float*)d_in[11];
  const float* bv     = (const float*)d_in[12];
  const float* Wp     = (const float*)d_in[13];
  const float* bp     = (const float*)d_in[14];
  const float* ln2_g  = (const float*)d_in[15];
  const float* ln2_b  = (const float*)d_in[16];
  const float* Wm1    = (const float*)d_in[17];
  const float* bm1    = (const float*)d_in[18];
  const float* Wm2    = (const float*)d_in[19];
  const float* bm2    = (const float*)d_in[20];
  const float* lnf_g  = (const float*)d_in[21];
  const float* lnf_b  = (const float*)d_in[22];
  const float* Wh1    = (const float*)d_in[23];
  const float* bh1    = (const float*)d_in[24];
  const float* Wh2    = (const float*)d_in[25];
  const float* bh2    = (const float*)d_in[26];

  char* wsp = (char*)d_ws;
  size_t off = 0;
  auto carve = [&](size_t bytes) -> char* {
    char* p = wsp + off;
    off += (bytes + 1023) & ~(size_t)1023;
    return p;
  };
  short* Wqkv_t = (short*)carve((size_t)NB_L * 3 * NB_D * NB_D * 2);
  short* Wp_t   = (short*)carve((size_t)NB_L * NB_D * NB_D * 2);
  short* Wm1_t  = (short*)carve((size_t)NB_L * NB_DFF * NB_D * 2);
  short* Wm2_t  = (short*)carve((size_t)NB_L * NB_D * NB_DFF * 2);
  float* x      = (float*)carve((size_t)NB_M * NB_D * 4);
  short* h      = (short*)carve((size_t)NB_M * NB_D * 2);
  short* qkvb   = (short*)carve((size_t)3 * NB_M * NB_D * 2);
  short* mlp    = (short*)carve((size_t)NB_M * NB_DFF * 2);
  short* Wh1t   = (short*)carve((size_t)128 * NB_D * 2);
  float* bh1p   = (float*)carve(128 * 4);
  short* attout = mlp;           // alias: dead before mlp is written
  float* hbuf   = (float*)qkvb;  // alias: qkv dead after last attention

  const dim3 thr(256), thr8(512);
  const size_t DD = (size_t)NB_D * NB_D;
  const size_t DF = (size_t)NB_D * NB_DFF;

  tconv_kernel<<<dim3(32, 32, NB_L), thr, 0, stream>>>(Wq, Wqkv_t + 0 * DD, NB_D, NB_D, DD, 3 * DD);
  tconv_kernel<<<dim3(32, 32, NB_L), thr, 0, stream>>>(Wk, Wqkv_t + 1 * DD, NB_D, NB_D, DD, 3 * DD);
  tconv_kernel<<<dim3(32, 32, NB_L), thr, 0, stream>>>(Wv, Wqkv_t + 2 * DD, NB_D, NB_D, DD, 3 * DD);
  tconv_kernel<<<dim3(32, 32, NB_L), thr, 0, stream>>>(Wp, Wp_t, NB_D, NB_D, DD, DD);
  tconv_kernel<<<dim3(128, 32, NB_L), thr, 0, stream>>>(Wm1, Wm1_t, NB_D, NB_DFF, DF, DF);
  tconv_kernel<<<dim3(32, 128, NB_L), thr, 0, stream>>>(Wm2, Wm2_t, NB_DFF, NB_D, DF, DF);
  whead_prep<<<512, thr, 0, stream>>>(Wh1, bh1, Wh1t, bh1p);

  embed_kernel<<<NB_M, thr, 0, stream>>>(states, goals, Wtok, btok, pos, x);

  for (int l = 0; l < NB_L; l++) {
    ln_kernel<short><<<NB_M, thr, 0, stream>>>(x, ln1_g + l * NB_D, ln1_b + l * NB_D, h);
    gemm8_qkv_kernel<<<dim3(NB_D / 256, NB_M / 128, 3), thr8, 0, stream>>>(
        h, Wqkv_t + (size_t)l * 3 * DD, bq + l * NB_D, bk + l * NB_D, bv + l * NB_D, qkvb);
    attn_kernel<<<dim3(NB_S / 64, NB_H, NB_B), thr, 0, stream>>>(qkvb, attout);
    gemm8<NB_D, 0, true, float><<<dim3(NB_D / 256, NB_M / 128), thr8, 0, stream>>>(
        attout, Wp_t + (size_t)l * DD, bp + l * NB_D, x, x, NB_D);
    ln_kernel<short><<<NB_M, thr, 0, stream>>>(x, ln2_g + l * NB_D, ln2_b + l * NB_D, h);
    gemm8<NB_D, 1, false, short><<<dim3(NB_DFF / 256, NB_M / 128), thr8, 0, stream>>>(
        h, Wm1_t + (size_t)l * DF, bm1 + l * NB_DFF, nullptr, mlp, NB_DFF);
    gemm8<NB_DFF, 0, true, float><<<dim3(NB_D / 256, NB_M / 128), thr8, 0, stream>>>(
        mlp, Wm2_t + (size_t)l * DF, bm2 + l * NB_D, x, x, NB_D);
  }

  ln_kernel<short><<<NB_M, thr, 0, stream>>>(x, lnf_g, lnf_b, h);
  gemm_bt<2, false, float><<<dim3(1, NB_M / 128), thr, 0, stream>>>(
      h, Wh1t, bh1p, nullptr, hbuf, 128, NB_D);
  head2_kernel<<<NB_M / 8, thr, 0, stream>>>(hbuf, Wh2, bh2, (float*)d_out);
}